// Round 4
// baseline (233.480 us; speedup 1.0000x reference)
//
#include <hip/hip_runtime.h>
#include <stdint.h>

// DIAGNOSTIC ROUND: kernels are R2's exact structures (best measured:
// 182.9 us) wrapped in an idempotent rep=10 loop so each dispatch inflates
// ~10x and becomes visible in rocprof's top-5 (the 40 us poison fills have
// hidden our kernels for 3 rounds). Repeats recompute and overwrite the
// SAME outputs -- correctness unchanged. dur_us will regress this round;
// next round reads the counters and strips the rep loop.
//
// Pre-committed interpretation:
//  - k1 dispatch ~60-90 us + FETCH~33MB  -> cold-BW-bound; attack gaps only
//  - k1 dispatch ~150-200 us, VALUBusy<50 -> latency-bound; more MLP
//  - VALUBusy>80                          -> VALU-bound; fatter tiles
#define H4_ 4096
#define B_  16
#define REP_ 10

// ---- K1: ifgo partials. part[s][b][j] f32. grid = 1024 x 256 thr.
// Block (ct, s): 32 consecutive cols j0 = ct*32, K-chunk s (256 rows;
// s 0..3 = Wi/x, 4..7 = Wh/h). s = bl&7 so each XCD owns one K-slice (4 MB).
__global__ __launch_bounds__(256) void k1_gemm(
    const float* __restrict__ x, const float* __restrict__ h,
    const float* __restrict__ Wi, const float* __restrict__ Wh,
    float* __restrict__ part)
{
    __shared__ float a_lds[256][16];      // 16 KB: A chunk, [k_local][batch]
    __shared__ float red[8][16][32];      // 16 KB: [k-stripe][b][c]

    const int s  = blockIdx.x & 7;
    const int ct = blockIdx.x >> 3;
    const int j0 = ct * 32;
    const int t  = threadIdx.x;
    const int c8 = t & 7;                 // col quad index (8 x 4 cols = 32)
    const int bq = (t >> 3) & 3;          // batch quad
    const int ks = t >> 5;                // k-stripe 0..7 (32 rows each)

    const float* A  = (s < 4) ? x : h;    // [16][1024] f32
    const float* W  = (s < 4) ? Wi : Wh;  // [1024][4096] f32
    const int    e0 = (s & 3) * 256;

    for (int rep = 0; rep < REP_; ++rep) {
        float acc[4][4];
        #pragma unroll
        for (int r = 0; r < 4; r++)
            #pragma unroll
            for (int c = 0; c < 4; c++) acc[r][c] = 0.f;

        // stage A chunk -> LDS: a_lds[kl][b] = A[b][e0+kl] (zero-conflict)
        {
            const int b = t & 15, kc = t >> 4;        // 16 k's per thread
            const float* src = A + b * 1024 + e0 + kc * 16;  // 64B aligned
            float4 v0 = *(const float4*)(src);
            float4 v1 = *(const float4*)(src + 4);
            float4 v2 = *(const float4*)(src + 8);
            float4 v3 = *(const float4*)(src + 12);
            const float vv[16] = { v0.x, v0.y, v0.z, v0.w, v1.x, v1.y, v1.z, v1.w,
                                   v2.x, v2.y, v2.z, v2.w, v3.x, v3.y, v3.z, v3.w };
            #pragma unroll
            for (int j = 0; j < 16; j++) a_lds[kc * 16 + j][b] = vv[j];
        }
        __syncthreads();   // sync1: a_lds ready (also fences prior rep's red reads)

        const float* wp = W + (size_t)e0 * H4_ + j0 + c8 * 4;
        #pragma unroll 8
        for (int i = 0; i < 32; i++) {
            const int kl = ks * 32 + i;
            float4 w = *(const float4*)(wp + (size_t)kl * H4_);  // 4 cols
            float4 a = *(const float4*)&a_lds[kl][bq * 4];       // 4 batches
            acc[0][0] += a.x * w.x; acc[0][1] += a.x * w.y; acc[0][2] += a.x * w.z; acc[0][3] += a.x * w.w;
            acc[1][0] += a.y * w.x; acc[1][1] += a.y * w.y; acc[1][2] += a.y * w.z; acc[1][3] += a.y * w.w;
            acc[2][0] += a.z * w.x; acc[2][1] += a.z * w.y; acc[2][2] += a.z * w.z; acc[2][3] += a.z * w.w;
            acc[3][0] += a.w * w.x; acc[3][1] += a.w * w.y; acc[3][2] += a.w * w.z; acc[3][3] += a.w * w.w;
        }

        // cross-stripe reduction (8 ks)
        #pragma unroll
        for (int r = 0; r < 4; r++)
            *(float4*)&red[ks][bq * 4 + r][c8 * 4] =
                make_float4(acc[r][0], acc[r][1], acc[r][2], acc[r][3]);
        __syncthreads();   // sync2: red ready; a_lds reads done -> reusable
        {
            const int b = t >> 4, c = t & 15;   // cols c and c+16
            float s0 = 0.f, s1 = 0.f;
            #pragma unroll
            for (int kk = 0; kk < 8; kk++) {
                s0 += red[kk][b][c];
                s1 += red[kk][b][c + 16];
            }
            float* dst = part + ((size_t)s * B_ + b) * H4_ + j0;
            dst[c]      = s0;
            dst[c + 16] = s1;
        }
        // next rep's sync1 protects red against early rewrite
    }
}

// ---- K2: sum 8 split partials + biases, activations. out = [h_new | c_new]
__global__ __launch_bounds__(256) void k2_act(
    const float* __restrict__ part, const float* __restrict__ c,
    const float* __restrict__ Wi_b, const float* __restrict__ Wh_b,
    float* __restrict__ out)
{
    const int tg = blockIdx.x * 256 + threadIdx.x;   // 0..16383
    const int b  = tg >> 10;
    const int j  = tg & 1023;

    for (int rep = 0; rep < REP_; ++rep) {
        float g4[4];
        #pragma unroll
        for (int g = 0; g < 4; g++) {
            const int col = g * 1024 + j;
            float acc = Wi_b[col] + Wh_b[col];
            #pragma unroll
            for (int ss = 0; ss < 8; ss++)
                acc += part[((size_t)ss * B_ + b) * H4_ + col];
            g4[g] = acc;
        }
        const float ig = 1.f / (1.f + __expf(-g4[0]));
        const float fg = 1.f / (1.f + __expf(-g4[1]));
        const float gg = tanhf(g4[2]);
        const float og = 1.f / (1.f + __expf(-g4[3]));
        const float cv = c[tg];
        const float cn = fg * cv + ig * gg;
        const float hn = og * tanhf(cn);
        out[tg]         = hn;
        out[16384 + tg] = cn;
    }
}

// ---- Fallback: fully fused, zero workspace (round-1 kernel, known-correct).
__global__ __launch_bounds__(256) void k_fused2(
    const float* __restrict__ x, const float* __restrict__ h,
    const float* __restrict__ cin,
    const float* __restrict__ Wi, const float* __restrict__ Wh,
    const float* __restrict__ Wi_b, const float* __restrict__ Wh_b,
    float* __restrict__ out)
{
    __shared__ float a_lds[256][16];
    __shared__ float red[16][16][16];
    __shared__ float gsum[16][16];

    const int bl = blockIdx.x;
    const int j0 = (bl & 7) * 128 + (bl >> 3) * 4;
    const int t  = threadIdx.x;
    const int g  = t & 3;
    const int bq = (t >> 2) & 3;
    const int ks = t >> 4;

    float acc[4][4];
    #pragma unroll
    for (int r = 0; r < 4; r++)
        #pragma unroll
        for (int c = 0; c < 4; c++) acc[r][c] = 0.f;

    for (int m = 0; m < 8; ++m) {
        const float* A  = (m < 4) ? x : h;
        const float* W  = (m < 4) ? Wi : Wh;
        const int    e0 = (m & 3) * 256;
        {
            const int b = t & 15, kc = t >> 4;
            const float* src = A + b * 1024 + e0 + kc * 16;
            float4 v0 = *(const float4*)(src);
            float4 v1 = *(const float4*)(src + 4);
            float4 v2 = *(const float4*)(src + 8);
            float4 v3 = *(const float4*)(src + 12);
            const float vv[16] = { v0.x, v0.y, v0.z, v0.w, v1.x, v1.y, v1.z, v1.w,
                                   v2.x, v2.y, v2.z, v2.w, v3.x, v3.y, v3.z, v3.w };
            #pragma unroll
            for (int jj = 0; jj < 16; jj++) a_lds[kc * 16 + jj][b] = vv[jj];
        }
        __syncthreads();
        const float* wp = W + (size_t)e0 * H4_ + g * 1024 + j0;
        #pragma unroll 4
        for (int i = 0; i < 16; i++) {
            const int kl = ks * 16 + i;
            float4 w = *(const float4*)(wp + (size_t)kl * H4_);
            float4 a = *(const float4*)&a_lds[kl][bq * 4];
            acc[0][0] += a.x * w.x; acc[0][1] += a.x * w.y; acc[0][2] += a.x * w.z; acc[0][3] += a.x * w.w;
            acc[1][0] += a.y * w.x; acc[1][1] += a.y * w.y; acc[1][2] += a.y * w.z; acc[1][3] += a.y * w.w;
            acc[2][0] += a.z * w.x; acc[2][1] += a.z * w.y; acc[2][2] += a.z * w.z; acc[2][3] += a.z * w.w;
            acc[3][0] += a.w * w.x; acc[3][1] += a.w * w.y; acc[3][2] += a.w * w.z; acc[3][3] += a.w * w.w;
        }
        __syncthreads();
    }

    #pragma unroll
    for (int g = 0; g < 4; g++) {
        ;
    }
    #pragma unroll
    for (int r = 0; r < 4; r++)
        *(float4*)&red[ks][bq * 4 + r][g * 4] =
            make_float4(acc[r][0], acc[r][1], acc[r][2], acc[r][3]);
    __syncthreads();
    {
        const int b = t >> 4, c16 = t & 15;
        float sum = 0.f;
        #pragma unroll
        for (int kk = 0; kk < 16; kk++) sum += red[kk][b][c16];
        gsum[b][c16] = sum;
    }
    __syncthreads();

    if (t < 64) {
        const int b = t >> 2, jj = t & 3;
        const int j = j0 + jj;
        const float s0 = gsum[b][jj]      + Wi_b[j]        + Wh_b[j];
        const float s1 = gsum[b][4 + jj]  + Wi_b[1024 + j] + Wh_b[1024 + j];
        const float s2 = gsum[b][8 + jj]  + Wi_b[2048 + j] + Wh_b[2048 + j];
        const float s3 = gsum[b][12 + jj] + Wi_b[3072 + j] + Wh_b[3072 + j];
        const float ig = 1.f / (1.f + __expf(-s0));
        const float fg = 1.f / (1.f + __expf(-s1));
        const float gg = tanhf(s2);
        const float og = 1.f / (1.f + __expf(-s3));
        const float cv = cin[b * 1024 + j];
        const float cn = fg * cv + ig * gg;
        const float hn = og * tanhf(cn);
        out[b * 1024 + j]         = hn;
        out[16384 + b * 1024 + j] = cn;
    }
}

extern "C" void kernel_launch(void* const* d_in, const int* in_sizes, int n_in,
                              void* d_out, int out_size, void* d_ws, size_t ws_size,
                              hipStream_t stream) {
    (void)in_sizes; (void)n_in; (void)out_size;
    const float* x    = (const float*)d_in[0];
    const float* h    = (const float*)d_in[1];
    const float* c    = (const float*)d_in[2];
    // d_in[3] = context (dead: multiplied by 0 in reference)
    const float* Wi   = (const float*)d_in[4];
    const float* Wi_b = (const float*)d_in[5];
    const float* Wh   = (const float*)d_in[6];
    const float* Wh_b = (const float*)d_in[7];
    // d_in[8..11] = AZ_* (dead)

    float* part = (float*)d_ws;
    float* out  = (float*)d_out;

    const size_t need = 8ull * B_ * H4_ * sizeof(float);   // 2 MB
    if (ws_size >= need) {
        k1_gemm<<<1024, 256, 0, stream>>>(x, h, Wi, Wh, part);
        k2_act<<<64, 256, 0, stream>>>(part, c, Wi_b, Wh_b, out);
    } else {
        k_fused2<<<64 * 4, 256, 0, stream>>>(x, h, c, Wi, Wh, Wi_b, Wh_b, out);
    }
}

// Round 5
// 191.111 us; speedup vs baseline: 1.2217x; 1.2217x over previous
//
#include <hip/hip_runtime.h>
#include <stdint.h>

// Geometry: B=16, E=H=1024, H4=4096, K_total = E+H = 2048. All f32.
//
// Evidence so far:
//  - Harness fixed overhead ~150-156 us/iter (256 MiB poison fill @40us +
//    resets/gaps). dur_us = fixed + our kernels. Untouchable.
//  - The poison fill streams 256 MiB -> L2 AND L3 fully evicted every iter:
//    production k1 is ALWAYS cold. Cross-iteration cache residency is dead.
//  - R4 rep-10 diagnostic: k1 VALUBusy 35%, Occupancy 39%, ~7.8 us/rep even
//    warm, bank conflicts negligible (1.4%) => LATENCY-BOUND (world 2).
//
// R5 fix: double wave supply. LDS 32KB -> 16KB (union a_lds/red), grid
// 1024 -> 2048 blocks (16 K-chunks of 128 rows), __launch_bounds__(256,8)
// caps VGPR at 64 => 8 blocks/CU = 32 waves/CU (vs 4 blocks/16 waves).
#define H4_ 4096
#define B_  16
#define SPLITS_ 16    // 128 K-rows per split; part = [16][16][4096] = 4 MB

// ---- K1: ifgo partials. part[s][b][j] f32. grid = 2048 x 256 thr.
// Block (ct, s): cols j0 = ct*32 (one 128B line), K-chunk s of 128 rows
// (s 0..7 = Wi/x, 8..15 = Wh/h). s = bl & 15 so XCD (bl%8) sees chunks
// {s, s+8} = 2MB Wi + 2MB Wh (harmless cold, helps any warm reuse).
__global__ __launch_bounds__(256, 8) void k1_gemm(
    const float* __restrict__ x, const float* __restrict__ h,
    const float* __restrict__ Wi, const float* __restrict__ Wh,
    float* __restrict__ part)
{
    __shared__ union {
        float a[128][16];                // 8 KB: A chunk, [k_local][batch]
        float red[8][16][32];            // 16 KB: [k-stripe][b][c]
    } sm;                                // union => 16 KB/block, 8 blocks/CU

    const int s  = blockIdx.x & 15;      // K-chunk
    const int ct = blockIdx.x >> 4;      // 0..127 col tile
    const int j0 = ct * 32;
    const int t  = threadIdx.x;
    const int c8 = t & 7;                // col quad index (8 x 4 cols = 32)
    const int bq = (t >> 3) & 3;         // batch quad
    const int ks = t >> 5;               // k-stripe 0..7 (16 rows each)

    const float* A  = (s < 8) ? x : h;   // [16][1024] f32
    const float* W  = (s < 8) ? Wi : Wh; // [1024][4096] f32
    const int    e0 = (s & 7) * 128;

    float acc[4][4];
    #pragma unroll
    for (int r = 0; r < 4; r++)
        #pragma unroll
        for (int c = 0; c < 4; c++) acc[r][c] = 0.f;

    // stage A chunk -> LDS: sm.a[kl][b] = A[b][e0+kl]
    {
        const int b = t & 15, kc = t >> 4;        // 8 k's per thread
        const float* src = A + b * 1024 + e0 + kc * 8;   // 32B aligned
        float4 v0 = *(const float4*)(src);
        float4 v1 = *(const float4*)(src + 4);
        const float vv[8] = { v0.x, v0.y, v0.z, v0.w, v1.x, v1.y, v1.z, v1.w };
        #pragma unroll
        for (int j = 0; j < 8; j++) sm.a[kc * 8 + j][b] = vv[j];
    }
    __syncthreads();

    // main loop: 16 rows per stripe, 1 global float4 + 1 lds float4 + 16 FMA
    const float* wp = W + (size_t)e0 * H4_ + j0 + c8 * 4;
    #pragma unroll 8
    for (int i = 0; i < 16; i++) {
        const int kl = ks * 16 + i;
        float4 w = *(const float4*)(wp + (size_t)kl * H4_);  // 4 cols, 16B
        float4 a = *(const float4*)&sm.a[kl][bq * 4];        // 4 batches
        acc[0][0] += a.x * w.x; acc[0][1] += a.x * w.y; acc[0][2] += a.x * w.z; acc[0][3] += a.x * w.w;
        acc[1][0] += a.y * w.x; acc[1][1] += a.y * w.y; acc[1][2] += a.y * w.z; acc[1][3] += a.y * w.w;
        acc[2][0] += a.z * w.x; acc[2][1] += a.z * w.y; acc[2][2] += a.z * w.z; acc[2][3] += a.z * w.w;
        acc[3][0] += a.w * w.x; acc[3][1] += a.w * w.y; acc[3][2] += a.w * w.z; acc[3][3] += a.w * w.w;
    }
    __syncthreads();   // a-reads done before red aliases the same LDS

    // cross-stripe reduction (8 ks)
    #pragma unroll
    for (int r = 0; r < 4; r++)
        *(float4*)&sm.red[ks][bq * 4 + r][c8 * 4] =
            make_float4(acc[r][0], acc[r][1], acc[r][2], acc[r][3]);
    __syncthreads();
    {
        const int b = t >> 4, c = t & 15;   // each thread: cols c and c+16
        float s0 = 0.f, s1 = 0.f;
        #pragma unroll
        for (int kk = 0; kk < 8; kk++) {
            s0 += sm.red[kk][b][c];
            s1 += sm.red[kk][b][c + 16];
        }
        float* dst = part + ((size_t)s * B_ + b) * H4_ + j0;
        dst[c]      = s0;
        dst[c + 16] = s1;
    }
}

// ---- K2: sum 16 split partials + biases, activations. out = [h_new | c_new]
__global__ __launch_bounds__(256) void k2_act(
    const float* __restrict__ part, const float* __restrict__ c,
    const float* __restrict__ Wi_b, const float* __restrict__ Wh_b,
    float* __restrict__ out)
{
    const int tg = blockIdx.x * 256 + threadIdx.x;   // 0..16383
    const int b  = tg >> 10;
    const int j  = tg & 1023;

    float g4[4];
    #pragma unroll
    for (int g = 0; g < 4; g++) {
        const int col = g * 1024 + j;
        float acc = Wi_b[col] + Wh_b[col];
        #pragma unroll 4
        for (int ss = 0; ss < SPLITS_; ss++)
            acc += part[((size_t)ss * B_ + b) * H4_ + col];
        g4[g] = acc;
    }
    const float ig = 1.f / (1.f + __expf(-g4[0]));
    const float fg = 1.f / (1.f + __expf(-g4[1]));
    const float gg = tanhf(g4[2]);
    const float og = 1.f / (1.f + __expf(-g4[3]));
    const float cv = c[tg];
    const float cn = fg * cv + ig * gg;
    const float hn = og * tanhf(cn);
    out[tg]         = hn;
    out[16384 + tg] = cn;
}

// ---- Fallback: fully fused, zero workspace (round-1 kernel, known-correct).
__global__ __launch_bounds__(256) void k_fused2(
    const float* __restrict__ x, const float* __restrict__ h,
    const float* __restrict__ cin,
    const float* __restrict__ Wi, const float* __restrict__ Wh,
    const float* __restrict__ Wi_b, const float* __restrict__ Wh_b,
    float* __restrict__ out)
{
    __shared__ float a_lds[256][16];
    __shared__ float red[16][16][16];
    __shared__ float gsum[16][16];

    const int bl = blockIdx.x;
    const int j0 = (bl & 7) * 128 + (bl >> 3) * 4;
    const int t  = threadIdx.x;
    const int g  = t & 3;
    const int bq = (t >> 2) & 3;
    const int ks = t >> 4;

    float acc[4][4];
    #pragma unroll
    for (int r = 0; r < 4; r++)
        #pragma unroll
        for (int c = 0; c < 4; c++) acc[r][c] = 0.f;

    for (int m = 0; m < 8; ++m) {
        const float* A  = (m < 4) ? x : h;
        const float* W  = (m < 4) ? Wi : Wh;
        const int    e0 = (m & 3) * 256;
        {
            const int b = t & 15, kc = t >> 4;
            const float* src = A + b * 1024 + e0 + kc * 16;
            float4 v0 = *(const float4*)(src);
            float4 v1 = *(const float4*)(src + 4);
            float4 v2 = *(const float4*)(src + 8);
            float4 v3 = *(const float4*)(src + 12);
            const float vv[16] = { v0.x, v0.y, v0.z, v0.w, v1.x, v1.y, v1.z, v1.w,
                                   v2.x, v2.y, v2.z, v2.w, v3.x, v3.y, v3.z, v3.w };
            #pragma unroll
            for (int jj = 0; jj < 16; jj++) a_lds[kc * 16 + jj][b] = vv[jj];
        }
        __syncthreads();
        const float* wp = W + (size_t)e0 * H4_ + g * 1024 + j0;
        #pragma unroll 4
        for (int i = 0; i < 16; i++) {
            const int kl = ks * 16 + i;
            float4 w = *(const float4*)(wp + (size_t)kl * H4_);
            float4 a = *(const float4*)&a_lds[kl][bq * 4];
            acc[0][0] += a.x * w.x; acc[0][1] += a.x * w.y; acc[0][2] += a.x * w.z; acc[0][3] += a.x * w.w;
            acc[1][0] += a.y * w.x; acc[1][1] += a.y * w.y; acc[1][2] += a.y * w.z; acc[1][3] += a.y * w.w;
            acc[2][0] += a.z * w.x; acc[2][1] += a.z * w.y; acc[2][2] += a.z * w.z; acc[2][3] += a.z * w.w;
            acc[3][0] += a.w * w.x; acc[3][1] += a.w * w.y; acc[3][2] += a.w * w.z; acc[3][3] += a.w * w.w;
        }
        __syncthreads();
    }

    #pragma unroll
    for (int r = 0; r < 4; r++)
        *(float4*)&red[ks][bq * 4 + r][g * 4] =
            make_float4(acc[r][0], acc[r][1], acc[r][2], acc[r][3]);
    __syncthreads();
    {
        const int b = t >> 4, c16 = t & 15;
        float sum = 0.f;
        #pragma unroll
        for (int kk = 0; kk < 16; kk++) sum += red[kk][b][c16];
        gsum[b][c16] = sum;
    }
    __syncthreads();

    if (t < 64) {
        const int b = t >> 2, jj = t & 3;
        const int j = j0 + jj;
        const float s0 = gsum[b][jj]      + Wi_b[j]        + Wh_b[j];
        const float s1 = gsum[b][4 + jj]  + Wi_b[1024 + j] + Wh_b[1024 + j];
        const float s2 = gsum[b][8 + jj]  + Wi_b[2048 + j] + Wh_b[2048 + j];
        const float s3 = gsum[b][12 + jj] + Wi_b[3072 + j] + Wh_b[3072 + j];
        const float ig = 1.f / (1.f + __expf(-s0));
        const float fg = 1.f / (1.f + __expf(-s1));
        const float gg = tanhf(s2);
        const float og = 1.f / (1.f + __expf(-s3));
        const float cv = cin[b * 1024 + j];
        const float cn = fg * cv + ig * gg;
        const float hn = og * tanhf(cn);
        out[b * 1024 + j]         = hn;
        out[16384 + b * 1024 + j] = cn;
    }
}

extern "C" void kernel_launch(void* const* d_in, const int* in_sizes, int n_in,
                              void* d_out, int out_size, void* d_ws, size_t ws_size,
                              hipStream_t stream) {
    (void)in_sizes; (void)n_in; (void)out_size;
    const float* x    = (const float*)d_in[0];
    const float* h    = (const float*)d_in[1];
    const float* c    = (const float*)d_in[2];
    // d_in[3] = context (dead: multiplied by 0 in reference)
    const float* Wi   = (const float*)d_in[4];
    const float* Wi_b = (const float*)d_in[5];
    const float* Wh   = (const float*)d_in[6];
    const float* Wh_b = (const float*)d_in[7];
    // d_in[8..11] = AZ_* (dead)

    float* part = (float*)d_ws;
    float* out  = (float*)d_out;

    const size_t need = (size_t)SPLITS_ * B_ * H4_ * sizeof(float);  // 4 MB
    if (ws_size >= need) {
        k1_gemm<<<2048, 256, 0, stream>>>(x, h, Wi, Wh, part);
        k2_act<<<64, 256, 0, stream>>>(part, c, Wi_b, Wh_b, out);
    } else {
        k_fused2<<<64 * 4, 256, 0, stream>>>(x, h, c, Wi, Wh, Wi_b, Wh_b, out);
    }
}